// Round 6
// baseline (89.841 us; speedup 1.0000x reference)
//
#include <hip/hip_runtime.h>

// Problem constants (match reference setup_inputs)
#define N_IN    512
#define NLAYERS 5
#define M_NODES 2048
#define FAN     32
#define B_BATCH 1024
#define E_EDGES (M_NODES * FAN)              // 65536
#define N_TOTAL (N_IN + NLAYERS * M_NODES)   // 10752
#define PREFIX4 (N_IN + 4 * M_NODES)         // 8704 gatherable nodes

// R20: depth-8 chunk prefetch. Evidence: fill 41.2 us is unconditional
// (R19: d_ws untouched, fill persists); controllable = pack ~5.5 + net
// ~40.5. R17's b32 run fit (instr x 5.8cy + conflicts) with NO latency
// term at 32 waves/CU; R16/R19's b64 config at 16 waves/CU has 15-25 us
// above its DS-throughput model -- candidate: vmcnt stalls on the depth-1
// JIT prefetch (L2 latency ~200-400cy, only ~60cy compute cover per step).
// Fix: issue all 8 uint4 chunk loads of a round upfront into named regs,
// consume in issue order -> compiler emits counted vmcnt(7..0); only the
// first chunk's latency is exposed. Everything else R19 verbatim (87.27us,
// absmax 0.0078): CB=4, g_pck static global, 16-pair-bank sort, f16 acts,
// b64 gathers + v_fma_mix_f32.
// Known fixed floor inside dur: ~41 us harness d_ws re-poison fill.
#define CB      4
#define NBLK    (B_BATCH / CB)               // 256 blocks
#define GROUPS  (M_NODES / 64)               // 32 node-groups of 64 per layer
#define ECH     (FAN / 4)                    // 8 uint4 edge-chunks per node

typedef unsigned short u16;
typedef unsigned int   u32;

// Packed edges live in the .so's device image (d_ws poison is unconditional,
// but g_pck also frees us from any ws-layout assumptions).
__device__ u32 g_pck[NLAYERS * E_EDGES];     // 1.31 MB, rewritten every call

// fp32 -> 15-bit (sign+exp+6 mantissa) in bits [31:17], RNE (weight pack)
__device__ __forceinline__ u32 f2bf15_hi(float f) {
    u32 b = __float_as_uint(f);
    return (b + 0xFFFFu + ((b >> 17) & 1u)) & 0xFFFE0000u;
}

typedef __fp16 h2 __attribute__((ext_vector_type(2)));
// two f32 -> packed 2xf16 (RTZ) in one v_cvt_pkrtz_f16_f32
__device__ __forceinline__ u32 pk_f16(float a, float b) {
    h2 r = __builtin_amdgcn_cvt_pkrtz(a, b);
    u32 u;
    __builtin_memcpy(&u, &r, 4);
    return u;
}

// ---------------------------------------------------------------------------
// Parallel pack+bank-sort (R14 verbatim). One block per (layer, group of 64
// nodes). word = f2bf15_hi(w) | (src<<3); per node counting-sort by
// pair-bank key (src & 15) + rotation by (node & 31) so wave-gathers spread
// over all 32 LDS banks. Output: g_pck[lg*2048 + ec*256 + lane*4 + c].
// ---------------------------------------------------------------------------
__global__ __launch_bounds__(1024) void pack_edges(
    const float* __restrict__ w,             // (L, E)
    const int* __restrict__ src) {           // (L, E)
    __shared__ u32 s_sorted[64][32];
    __shared__ int s_cnt[64][16];
    __shared__ int s_start[64][16];

    const int t  = threadIdx.x;
    const int lg = blockIdx.x;               // l*GROUPS + g
    const size_t ebase = (size_t)lg * 2048;  // global edge base of this group

    if (t < 64 * 16) ((int*)s_cnt)[t] = 0;
    __syncthreads();

    // pass 1: load 2 consecutive edges (coalesced int2/float2), histogram
    const int e0 = t * 2;                    // local edge idx; node = e0>>5
    const int node = e0 >> 5;
    const int2   s2 = *reinterpret_cast<const int2*>(src + ebase + e0);
    const float2 w2 = *reinterpret_cast<const float2*>(w + ebase + e0);
    const u32 wd0 = f2bf15_hi(w2.x) | ((u32)s2.x << 3);
    const u32 wd1 = f2bf15_hi(w2.y) | ((u32)s2.y << 3);
    atomicAdd(&s_cnt[node][s2.x & 15], 1);
    atomicAdd(&s_cnt[node][s2.y & 15], 1);
    __syncthreads();

    // exclusive scan of each node's 16 counters (64 threads, serial 16)
    if (t < 64) {
        int acc = 0;
#pragma unroll
        for (int i = 0; i < 16; ++i) {
            s_start[t][i] = acc;
            acc += s_cnt[t][i];
        }
    }
    __syncthreads();

    // pass 2: rank within bank-key -> rotated slot kp, scatter into LDS tile
    const int rot = node & 31;
    {
        const int r0 = atomicAdd(&s_start[node][(wd0 >> 3) & 15], 1);
        s_sorted[node][(r0 + rot) & 31] = wd0;
        const int r1 = atomicAdd(&s_start[node][(wd1 >> 3) & 15], 1);
        s_sorted[node][(r1 + rot) & 31] = wd1;
    }
    __syncthreads();

    // write out linearly (fully coalesced): p = ec*256 + lane*4 + c
#pragma unroll
    for (int i = 0; i < 2; ++i) {
        const int p    = t + i * 1024;
        const int lane = (p >> 2) & 63;
        const int kp   = ((p >> 8) << 2) | (p & 3);   // ec*4 + c
        g_pck[ebase + p] = s_sorted[lane][kp];
    }
}

// one edge-chunk: 4 x (AND -> ds_read_b64) then 16 x v_fma_mix_f32
#define PROC_CHUNK(wd)                                                        \
    {                                                                         \
        const u32 ew0 = (wd).x, ew1 = (wd).y, ew2 = (wd).z, ew3 = (wd).w;     \
        const uint2 v0 = *reinterpret_cast<const uint2*>(vbase + (ew0 & 0x1FFF8u)); \
        const uint2 v1 = *reinterpret_cast<const uint2*>(vbase + (ew1 & 0x1FFF8u)); \
        const uint2 v2 = *reinterpret_cast<const uint2*>(vbase + (ew2 & 0x1FFF8u)); \
        const uint2 v3 = *reinterpret_cast<const uint2*>(vbase + (ew3 & 0x1FFF8u)); \
        const float wv0 = __uint_as_float(ew0 & 0xFFFE0000u);                 \
        const float wv1 = __uint_as_float(ew1 & 0xFFFE0000u);                 \
        const float wv2 = __uint_as_float(ew2 & 0xFFFE0000u);                 \
        const float wv3 = __uint_as_float(ew3 & 0xFFFE0000u);                 \
        FMA4(wv0, v0); FMA4(wv1, v1); FMA4(wv2, v2); FMA4(wv3, v3);           \
    }

#define FMA4(wv, v)                                                           \
    asm("v_fma_mix_f32 %0, %1, %2, %0 op_sel:[0,0,0] op_sel_hi:[0,1,0]"       \
        : "+v"(a0) : "v"(wv), "v"((v).x));                                    \
    asm("v_fma_mix_f32 %0, %1, %2, %0 op_sel:[0,1,0] op_sel_hi:[0,1,0]"       \
        : "+v"(a1) : "v"(wv), "v"((v).x));                                    \
    asm("v_fma_mix_f32 %0, %1, %2, %0 op_sel:[0,0,0] op_sel_hi:[0,1,0]"       \
        : "+v"(a2) : "v"(wv), "v"((v).y));                                    \
    asm("v_fma_mix_f32 %0, %1, %2, %0 op_sel:[0,1,0] op_sel_hi:[0,1,0]"       \
        : "+v"(a3) : "v"(wv), "v"((v).y));

// ---------------------------------------------------------------------------
// Persistent network kernel. Block blk owns batch rows 4*blk .. 4*blk+3.
// LDS vals2[n] = 4 x f16 (h0|h1<<16, h2|h3<<16), gatherable prefix only.
// Per layer: 2 sequential rounds x 1024 threads; per round: ALL 8 uint4
// chunk loads issued upfront into named regs (depth-8 prefetch, counted
// vmcnt waits), then 8 chunk steps consumed in issue order.
// ---------------------------------------------------------------------------
__global__ __launch_bounds__(1024) void net_kernel(
    const float* __restrict__ x,             // (B, N_IN) fp32
    const float* __restrict__ bias,          // (L, M) fp32
    float* __restrict__ out) {               // (B, M) fp32
    __shared__ uint2 vals2[PREFIX4];         // 69632 B

    const int t   = threadIdx.x;
    const int blk = blockIdx.x;

    if (t < N_IN) {
        const float v0 = x[(size_t)(CB * blk + 0) * N_IN + t];
        const float v1 = x[(size_t)(CB * blk + 1) * N_IN + t];
        const float v2 = x[(size_t)(CB * blk + 2) * N_IN + t];
        const float v3 = x[(size_t)(CB * blk + 3) * N_IN + t];
        vals2[t] = make_uint2(pk_f16(v0, v1), pk_f16(v2, v3));
    }

    const int g0    = t >> 6;                // group of node j0 = t
    const int lane6 = t & 63;
    const char* vbase = reinterpret_cast<const char*>(vals2);

    for (int l = 0; l < NLAYERS; ++l) {
        __syncthreads();
        const int base = N_IN + l * M_NODES;
#pragma unroll
        for (int r = 0; r < 2; ++r) {
            const int j = r * 1024 + t;
            const uint4* ep = reinterpret_cast<const uint4*>(g_pck) +
                              (size_t)(l * GROUPS + g0 + r * 16) * ECH * 64 +
                              lane6;
            const float bj = bias[l * M_NODES + j];
            float a0 = bj, a1 = bj, a2 = bj, a3 = bj;

            // depth-8 prefetch: issue all chunk loads, consume in order
            const uint4 w0 = ep[0 * 64];
            const uint4 w1 = ep[1 * 64];
            const uint4 w2 = ep[2 * 64];
            const uint4 w3 = ep[3 * 64];
            const uint4 w4 = ep[4 * 64];
            const uint4 w5 = ep[5 * 64];
            const uint4 w6 = ep[6 * 64];
            const uint4 w7 = ep[7 * 64];

            PROC_CHUNK(w0)
            PROC_CHUNK(w1)
            PROC_CHUNK(w2)
            PROC_CHUNK(w3)
            PROC_CHUNK(w4)
            PROC_CHUNK(w5)
            PROC_CHUNK(w6)
            PROC_CHUNK(w7)

            a0 = fmaxf(a0, 0.f);
            a1 = fmaxf(a1, 0.f);
            a2 = fmaxf(a2, 0.f);
            a3 = fmaxf(a3, 0.f);
            if (l < NLAYERS - 1) {
                vals2[base + j] = make_uint2(pk_f16(a0, a1), pk_f16(a2, a3));
            } else {
                out[(size_t)(CB * blk + 0) * M_NODES + j] = a0;
                out[(size_t)(CB * blk + 1) * M_NODES + j] = a1;
                out[(size_t)(CB * blk + 2) * M_NODES + j] = a2;
                out[(size_t)(CB * blk + 3) * M_NODES + j] = a3;
            }
        }
    }
}

extern "C" void kernel_launch(void* const* d_in, const int* in_sizes, int n_in,
                              void* d_out, int out_size, void* d_ws, size_t ws_size,
                              hipStream_t stream) {
    const float* x       = (const float*)d_in[0];   // (B, N_IN)
    const float* weights = (const float*)d_in[1];   // (L, E)
    const float* biases  = (const float*)d_in[2];   // (L, M)
    const int*   src_idx = (const int*)d_in[3];     // (L, E)
    // d_in[4] = dst_idx: structurally repeat(arange(M), FAN) -> segment j = e/FAN
    float* out = (float*)d_out;                     // (B, M) fp32
    (void)d_ws; (void)ws_size;                      // workspace unused (g_pck)

    // 1) parallel pack + bank-sort into the static device global
    pack_edges<<<NLAYERS * GROUPS, 1024, 0, stream>>>(weights, src_idx);

    // 2) persistent network: 256 blocks (1/CU), all layers in one kernel
    net_kernel<<<NBLK, 1024, 0, stream>>>(x, biases, out);
}